// Round 16
// baseline (46.979 us; speedup 1.0000x reference)
//
#include <hip/hip_runtime.h>

#define NN   2048
#define EE   65536
#define EDIM 64
#define LL   5
#define NP   ((size_t)NN * NN)   // 4,194,304 pairs
#define TGT  262144              // threads in pairs kernel (1024 x 256)
#define QS   0.375f
#define QINV 2.6666667f

__device__ __forceinline__ void gload_lds16(const void* g, void* l) {
  __builtin_amdgcn_global_load_lds(
      (const __attribute__((address_space(1))) void*)g,
      (__attribute__((address_space(3))) void*)l, 16, 0, 0);
}

// Kernel 1: dotsQ[l][e] = int8 round((attr[e]·ev[l]) / 0.375)  (copy 0).
__global__ __launch_bounds__(256) void dots_kernel(
    const float* __restrict__ edge_attr,
    const float* __restrict__ edge_vector,
    signed char* __restrict__ dotsQ) {
  const int lane = threadIdx.x & 63;
  const int wib  = threadIdx.x >> 6;
  const int dg   = lane & 15;
  const int es   = lane >> 4;
  const int e    = blockIdx.x * 16 + wib * 4 + es;

  const float4 a = *(const float4*)(edge_attr + e * EDIM + dg * 4);
  float d[LL];
#pragma unroll
  for (int l = 0; l < LL; ++l) {
    const float4 ev = *(const float4*)(edge_vector + l * EDIM + dg * 4);
    d[l] = a.x * ev.x + a.y * ev.y + a.z * ev.z + a.w * ev.w;
  }
#pragma unroll
  for (int s = 1; s <= 8; s <<= 1) {
#pragma unroll
    for (int l = 0; l < LL; ++l) d[l] += __shfl_xor(d[l], s, 64);
  }
  if (dg < LL) {
    const float dv = (dg == 0) ? d[0] : (dg == 1) ? d[1] : (dg == 2) ? d[2]
                   : (dg == 3) ? d[3] : d[4];
    const float qf = fminf(fmaxf(dv * QINV, -127.f), 127.f);
    dotsQ[dg * EE + e] = (signed char)__float2int_rn(qf);
  }
}

// Kernel 1b: replicate the 320 KB table to copies 1..7 (one per XCD) so
// pairs staging is XCD-L2-local instead of L3-served (the R14 wall: 335 MB
// of cross-XCD plane reads through Infinity Cache).
__global__ __launch_bounds__(256) void replicate_kernel(
    const signed char* __restrict__ src, signed char* __restrict__ dst) {
  const int i = blockIdx.x * 256 + threadIdx.x;   // uint2 id, 40960 total
  const uint2 v = ((const uint2*)src)[i];
#pragma unroll
  for (int c = 1; c < 8; ++c)
    ((uint2*)(dst + (size_t)c * (LL * EE)))[i] = v;
}

// Kernel 2: 256-thread WGs (VGPR cap 256 at 2 WGs/CU — out of the 64-cap
// trap that burned R6-R13), 64 KB LDS plane -> 2 WGs/CU overlap. 16 pairs/
// thread; idx read once, packed u16, pinned. Staging reads the XCD-local
// table copy (blockIdx & 7 matches HW round-robin block->XCD dispatch;
// wrong mapping costs locality only, never correctness).
__global__ __launch_bounds__(256, 2) void pairs_kernel(
    const int* __restrict__ ept,
    const signed char* __restrict__ dotsR,
    float* __restrict__ out) {
  __shared__ __align__(16) signed char tab[EE];   // 65,536 B
  const int ltid = threadIdx.x;
  const int tid  = blockIdx.x * 256 + ltid;       // 0..TGT-1
  const signed char* myrep = dotsR + (size_t)(blockIdx.x & 7) * (LL * EE);

  // ---- Load 80 indices (4 groups x 5 int4), pack u16 (2 ids/VGPR). ----
  unsigned pk[40];
  unsigned cp0 = 0u, cp1 = 0u;  // 4-bit valid counts, pairs 0..7 / 8..15
#pragma unroll
  for (int g = 0; g < 4; ++g) {
    const size_t gid = (size_t)g * TGT + (size_t)tid;
    const int4* p = (const int4*)(ept + gid * 20);
    int raw[20];
#pragma unroll
    for (int q = 0; q < 5; ++q) {
      const int4 v = p[q];
      raw[q * 4 + 0] = v.x; raw[q * 4 + 1] = v.y;
      raw[q * 4 + 2] = v.z; raw[q * 4 + 3] = v.w;
    }
#pragma unroll
    for (int s = 0; s < 20; ++s) {
      const int id = raw[s];
      const int k  = g * 4 + s / 5;              // global pair 0..15
      const unsigned m = (id >= 0) ? 1u : 0u;
      if (k < 8) cp0 += m << (k * 4); else cp1 += m << ((k - 8) * 4);
      const unsigned e16 = (id < 0) ? 0u : (unsigned)id;
      const int sg = g * 20 + s;                 // global slot = k*5 + l
      if ((sg & 1) == 0) pk[sg >> 1] = e16;
      else               pk[sg >> 1] |= (e16 << 16);
    }
  }
  // Pin: forbid per-pass rematerialization of the idx loads (R7 pathology).
  asm volatile("" : "+v"(pk[0]), "+v"(pk[1]), "+v"(pk[2]), "+v"(pk[3]),
                    "+v"(pk[4]), "+v"(pk[5]), "+v"(pk[6]), "+v"(pk[7]),
                    "+v"(pk[8]), "+v"(pk[9]), "+v"(pk[10]), "+v"(pk[11]),
                    "+v"(pk[12]), "+v"(pk[13]), "+v"(pk[14]), "+v"(pk[15]),
                    "+v"(pk[16]), "+v"(pk[17]), "+v"(pk[18]), "+v"(pk[19]));
  asm volatile("" : "+v"(pk[20]), "+v"(pk[21]), "+v"(pk[22]), "+v"(pk[23]),
                    "+v"(pk[24]), "+v"(pk[25]), "+v"(pk[26]), "+v"(pk[27]),
                    "+v"(pk[28]), "+v"(pk[29]), "+v"(pk[30]), "+v"(pk[31]),
                    "+v"(pk[32]), "+v"(pk[33]), "+v"(pk[34]), "+v"(pk[35]),
                    "+v"(pk[36]), "+v"(pk[37]), "+v"(pk[38]), "+v"(pk[39]),
                    "+v"(cp0), "+v"(cp1));

  int sum[16];
#pragma unroll
  for (int k = 0; k < 16; ++k) sum[k] = 0;
  int t0v[LL];

  // ---- 5 passes: stage plane l (64 KB, XCD-local), gather 16 slots. ----
#pragma unroll
  for (int l = 0; l < LL; ++l) {
    if (l) __syncthreads();                      // prior pass's gathers done
    const signed char* src = myrep + (size_t)l * EE;
#pragma unroll
    for (int r = 0; r < 16; ++r) {
      const int c = (r * 256 + ltid) * 16;       // 16-B chunk offset
      gload_lds16(src + c, tab + c);
    }
    __syncthreads();                             // drains vmcnt + visibility
    t0v[l] = (int)tab[0];                        // broadcast (correction)
#pragma unroll
    for (int k = 0; k < 16; ++k) {
      const int sg = k * LL + l;                 // compile-time
      const unsigned r = pk[sg >> 1];
      const unsigned id = (sg & 1) ? (r >> 16) : (r & 0xffffu);
      sum[k] += (int)tab[id];
    }
  }

  // ---- Suffix sums of tab0 per plane: S[m] = sum_{l>=m} t0v[l]. ----
  const int S4 = t0v[4];
  const int S3 = S4 + t0v[3];
  const int S2 = S3 + t0v[2];
  const int S1 = S2 + t0v[1];
  const int S0 = S1 + t0v[0];

  // ---- Finalize: subtract invalid-suffix, scale, divide, store. ----
#pragma unroll
  for (int g = 0; g < 4; ++g) {
    const size_t gid = (size_t)g * TGT + (size_t)tid;
    float rr[4];
#pragma unroll
    for (int j = 0; j < 4; ++j) {
      const int k = g * 4 + j;
      const unsigned cnt = (((k < 8) ? cp0 : cp1) >> ((k & 7) * 4)) & 15u;
      const int corr = (cnt == 5) ? 0
                     : (cnt == 4) ? S4
                     : (cnt == 3) ? S3
                     : (cnt == 2) ? S2
                     : (cnt == 1) ? S1 : S0;
      rr[j] = (QS * (float)(sum[k] - corr)) / ((float)cnt + 1e-10f);  // cnt==0 -> 0
    }
    ((float4*)out)[gid] = make_float4(rr[0], rr[1], rr[2], rr[3]);
  }
}

extern "C" void kernel_launch(void* const* d_in, const int* in_sizes, int n_in,
                              void* d_out, int out_size, void* d_ws, size_t ws_size,
                              hipStream_t stream) {
  // d_in order: x(unused), edge_attr, edge_vector, edge_paths_tensor, edge_paths_length(unused)
  const float* edge_attr   = (const float*)d_in[1];
  const float* edge_vector = (const float*)d_in[2];
  const int*   ept         = (const int*)d_in[3];
  float* out = (float*)d_out;
  signed char* dotsR = (signed char*)d_ws;   // 8 copies x L x E int8 = 2.6 MB

  dots_kernel<<<EE / 16, 256, 0, stream>>>(edge_attr, edge_vector, dotsR);
  replicate_kernel<<<160, 256, 0, stream>>>(dotsR, dotsR);

  // 1024 WGs x 256 threads, 16 pairs/thread; 64 KB LDS -> 2 WGs/CU resident.
  pairs_kernel<<<1024, 256, 0, stream>>>(ept, dotsR, out);
}

// Round 17
// 44.083 us; speedup vs baseline: 1.0657x; 1.0657x over previous
//
#include <hip/hip_runtime.h>

#define NN   2048
#define EE   65536
#define EDIM 64
#define LL   5
#define NWG  512
#define THR  512
#define TG   262144              // NWG*THR threads in pairs kernel
#define QS   0.375f
#define QINV 2.6666667f

// Kernel 1: dotsQ[l][e] = int8 round((attr[e]·ev[l]) / 0.375), planes of 64 KB.
__global__ __launch_bounds__(256) void dots_kernel(
    const float* __restrict__ edge_attr,
    const float* __restrict__ edge_vector,
    signed char* __restrict__ dotsQ) {
  const int lane = threadIdx.x & 63;
  const int wib  = threadIdx.x >> 6;
  const int dg   = lane & 15;
  const int es   = lane >> 4;
  const int e    = blockIdx.x * 16 + wib * 4 + es;

  const float4 a = *(const float4*)(edge_attr + e * EDIM + dg * 4);
  float d[LL];
#pragma unroll
  for (int l = 0; l < LL; ++l) {
    const float4 ev = *(const float4*)(edge_vector + l * EDIM + dg * 4);
    d[l] = a.x * ev.x + a.y * ev.y + a.z * ev.z + a.w * ev.w;
  }
#pragma unroll
  for (int s = 1; s <= 8; s <<= 1) {
#pragma unroll
    for (int l = 0; l < LL; ++l) d[l] += __shfl_xor(d[l], s, 64);
  }
  if (dg < LL) {
    const float dv = (dg == 0) ? d[0] : (dg == 1) ? d[1] : (dg == 2) ? d[2]
                   : (dg == 3) ? d[3] : d[4];
    const float qf = fminf(fmaxf(dv * QINV, -127.f), 127.f);
    dotsQ[dg * EE + e] = (signed char)__float2int_rn(qf);
  }
}

__device__ __forceinline__ void stage_plane(const signed char* __restrict__ dotsQ,
                                            int plane, signed char* lbuf, int ltid) {
#pragma unroll
  for (int r = 0; r < 8; ++r) {
    const int c = (r * THR + ltid) * 16;
    __builtin_amdgcn_global_load_lds(
        (const __attribute__((address_space(1))) void*)(dotsQ + (size_t)plane * EE + c),
        (__attribute__((address_space(3))) void*)(lbuf + c), 16, 0, 0);
  }
}

// Kernel 2: 16 pairs/thread with indices parked in LDS (idxs[5][4][512],
// 80 KB) — cross-pass register state collapses to sum[16]+2 count words, so
// the 64-VGPR remat/spill wall (R6-R10) is structurally gone, and WG count
// halves vs R14 (512 x 512thr x 16 pairs): staging TA-requests 21M -> 10.5M.
// Per pass: stage 64 KB plane (global_load_lds), ds_read_b64 idx slice
// (8 B lane stride = free 2-way), 16 ds_read_i8 gathers, int accumulate.
// Invalid ids -> 0; int-exact suffix-sum of tab[0] per plane corrects them.
__global__ __launch_bounds__(512, 2) void pairs_kernel(
    const int* __restrict__ ept,
    const signed char* __restrict__ dotsQ,
    float* __restrict__ out) {
  __shared__ __align__(16) signed char tab[EE];       // 64 KB table plane
  __shared__ __align__(16) uint2 idxs[LL][4][THR];    // 80 KB parked indices
  const int ltid = threadIdx.x;
  const int tid  = blockIdx.x * THR + ltid;           // 0..TG-1

  // Stage plane 0 immediately; its flight covers the idx load/pack phase.
  stage_plane(dotsQ, 0, tab, ltid);

  // ---- Load 80 indices (4 groups x 5 int4); pack u16 by l into LDS. ----
  unsigned cp0 = 0u, cp1 = 0u;  // 4-bit valid counts, pairs 0..7 / 8..15
#pragma unroll
  for (int g = 0; g < 4; ++g) {
    const size_t gid = (size_t)g * TG + (size_t)tid;
    const int4* p = (const int4*)(ept + gid * 20);
    int4 v[5];
#pragma unroll
    for (int q = 0; q < 5; ++q) v[q] = p[q];
#pragma unroll
    for (int l = 0; l < LL; ++l) {
      unsigned w0 = 0u, w1 = 0u;
#pragma unroll
      for (int j = 0; j < 4; ++j) {
        const int s = j * 5 + l;                       // 0..19, compile-time
        const int id = ((s & 3) == 0) ? v[s >> 2].x : ((s & 3) == 1) ? v[s >> 2].y
                     : ((s & 3) == 2) ? v[s >> 2].z : v[s >> 2].w;
        const unsigned m = (id >= 0) ? 1u : 0u;
        const int k = 4 * g + j;
        if (k < 8) cp0 += m << (k * 4); else cp1 += m << ((k - 8) * 4);
        const unsigned e16 = (id < 0) ? 0u : (unsigned)id;
        if (j < 2) w0 |= e16 << (j * 16); else w1 |= e16 << ((j - 2) * 16);
      }
      idxs[l][g][ltid] = make_uint2(w0, w1);
    }
    asm volatile("" ::: "memory");  // chunk g's loads (caps transient regs)
  }

  int sum[16];
#pragma unroll
  for (int k = 0; k < 16; ++k) sum[k] = 0;
  int t0v[LL];

  __syncthreads();  // plane-0 staging drained + idx writes visible

  // ---- 5 passes: gather from tab (plane l), then restage plane l+1. ----
#pragma unroll
  for (int l = 0; l < LL; ++l) {
    t0v[l] = (int)tab[0];                              // broadcast read
#pragma unroll
    for (int g = 0; g < 4; ++g) {
      const uint2 a = idxs[l][g][ltid];                // ds_read_b64, free 2-way
      sum[4 * g + 0] += (int)tab[a.x & 0xffffu];
      sum[4 * g + 1] += (int)tab[a.x >> 16];
      sum[4 * g + 2] += (int)tab[a.y & 0xffffu];
      sum[4 * g + 3] += (int)tab[a.y >> 16];
    }
    __syncthreads();                                   // all reads of tab done
    if (l < LL - 1) {
      stage_plane(dotsQ, l + 1, tab, ltid);
      __syncthreads();                                 // drains vmcnt + visibility
    }
  }

  // ---- Suffix sums of tab0 per plane: S[m] = sum_{l>=m} t0v[l]. ----
  const int S4 = t0v[4];
  const int S3 = S4 + t0v[3];
  const int S2 = S3 + t0v[2];
  const int S1 = S2 + t0v[1];
  const int S0 = S1 + t0v[0];

  // ---- Finalize: subtract invalid-suffix, scale, divide, store. ----
#pragma unroll
  for (int g = 0; g < 4; ++g) {
    const size_t gid = (size_t)g * TG + (size_t)tid;
    float rr[4];
#pragma unroll
    for (int j = 0; j < 4; ++j) {
      const int k = g * 4 + j;
      const unsigned cnt = (((k < 8) ? cp0 : cp1) >> ((k & 7) * 4)) & 15u;
      const int corr = (cnt == 5) ? 0
                     : (cnt == 4) ? S4
                     : (cnt == 3) ? S3
                     : (cnt == 2) ? S2
                     : (cnt == 1) ? S1 : S0;
      rr[j] = (QS * (float)(sum[k] - corr)) / ((float)cnt + 1e-10f);  // cnt==0 -> 0
    }
    ((float4*)out)[gid] = make_float4(rr[0], rr[1], rr[2], rr[3]);
  }
}

extern "C" void kernel_launch(void* const* d_in, const int* in_sizes, int n_in,
                              void* d_out, int out_size, void* d_ws, size_t ws_size,
                              hipStream_t stream) {
  // d_in order: x(unused), edge_attr, edge_vector, edge_paths_tensor, edge_paths_length(unused)
  const float* edge_attr   = (const float*)d_in[1];
  const float* edge_vector = (const float*)d_in[2];
  const int*   ept         = (const int*)d_in[3];
  float* out = (float*)d_out;
  signed char* dotsQ = (signed char*)d_ws;   // L x E int8 = 320 KB scratch

  dots_kernel<<<EE / 16, 256, 0, stream>>>(edge_attr, edge_vector, dotsQ);

  // 512 WGs x 512 threads, 16 pairs/thread; 144 KB LDS -> 1 WG/CU resident.
  pairs_kernel<<<NWG, THR, 0, stream>>>(ept, dotsQ, out);
}